// Round 12
// baseline (292.601 us; speedup 1.0000x reference)
//
#include <hip/hip_runtime.h>

typedef float v4f __attribute__((ext_vector_type(4)));

#define NB   32     // batch
#define NT   8      // timesteps
#define NC   128    // channels
#define NQ   256    // float4s per (H*W)=1024 plane
#define CRED 32     // C/red

// Cross-block mean publish: each channel mean (double) is split into two
// 64-bit words:  word = (seq << 32) | 32-bit-half-of-double-bits, seq = t+1.
// Data and version share ONE atomic location -> freshness is self-validating
// (no reliance on store-ack == LLC-complete; that was the R0 failure).
// One buffer slice PER STEP (write-once -> no WAR hazard) -> no arrive
// barrier: consumers spin directly on the data words (the poll IS the
// fetch). Zeroed per launch so seq=0 is invalid across graph replays.
#define NWORDS (NT * NB * NC * 2)   // step x batch x channel x {lo,hi}

__device__ unsigned long long g_xw[NWORDS];          // (seq<<32 | half) words

__global__ __launch_bounds__(256)
void lif_init() {
    int i = threadIdx.x + blockIdx.x * blockDim.x;
    if (i < NWORDS) g_xw[i] = 0ull;
}

// Raw barrier: LDS-only drain (lgkmcnt), NO vmcnt(0). Fused into one asm so
// no LDS access can be hoisted between the wait and the barrier. Waves
// waiting here do NOT drain their outstanding nontemporal stores.
#define LDS_BARRIER() asm volatile("s_waitcnt lgkmcnt(0)\n\ts_barrier" ::: "memory")

// ---------------------------------------------------------------------------
// R5: STORES AFTER THE POLL (fixing R4's wrong cut). vmcnt retires IN ORDER,
// so whatever is in a wave's VMEM queue when the poll waits gets drained on
// the critical path. R3 had publish+prefetch+16KB NT spike stores queued;
// R4 "specialized" the non-critical waves but left wave 0 (the only wave
// whose timing matters) draining its own stores, AND serialized the poll
// into 4 dependent spin loops (-5 us). This version keeps R3's parallel
// 256-lane poll and simply reorders each step:
//   phase A -> B1 -> publish -> prefetch -> POLL -> spike+store+reset -> B2
//   -> MLP -> B3.
// At poll time the queue holds only the publish (must land anyway) and the
// prefetch loads (must complete before next phase A anyway -- draining them
// inside the sibling-skew wait is free overlap). The spike stores issue
// after the poll and drain fire-and-forget over the next ~10 us step,
// never again on any wait path. A compiler memory barrier after the poll
// prevents hoisting the independent stores above the relaxed atomic loads.
// fma/psum/reduce/publish-bits/MLP-order/sigmoid untouched -> spikes and
// tau bit-identical to the harness-verified R3 kernel.
// Co-residency: ~56 VGPR @ __launch_bounds__(256,4) -> 8 blocks/CU capacity,
// 4 needed; all 1024 blocks resident; spin cannot deadlock.
// ---------------------------------------------------------------------------
__global__ __launch_bounds__(256, 4)
void dynamic_lif(const float* __restrict__ x,
                 const float* __restrict__ w1,
                 const float* __restrict__ b1,
                 const float* __restrict__ w2,
                 const float* __restrict__ b2,
                 float* __restrict__ out)
{
    const int bid = blockIdx.x;          // 0..1023
    const int b   = bid >> 5;            // batch
    const int c0  = (bid & 31) << 2;     // first of 4 channels
    const int tid = threadIdx.x;
    const int wv  = tid >> 6;
    const int ln  = tid & 63;

    __shared__ double       s_part[4][4];
    __shared__ unsigned int s_w[256];    // fetched 32-bit halves
    __shared__ float        s_tau;

    const v4f* __restrict__ x4 = (const v4f*)x;
    v4f* __restrict__ o4       = (v4f*)out;

    v4f mem[4];
    #pragma unroll
    for (int p = 0; p < 4; ++p) mem[p] = (v4f){0.f, 0.f, 0.f, 0.f};

    float tau = 0.5f;                    // TAU0

    v4f xv[4];
    #pragma unroll
    for (int p = 0; p < 4; ++p)
        xv[p] = __builtin_nontemporal_load(x4 + ((b * NT + 0) * NC + c0 + p) * NQ + tid);

    for (int t = 0; t < NT; ++t) {
        // ---- phase A: fma + plane-sum ONLY; mem keeps PRE-reset values ----
        double psum[4];
        #pragma unroll
        for (int p = 0; p < 4; ++p) {
            v4f m = mem[p];
            m.x = fmaf(m.x, tau, xv[p].x);
            m.y = fmaf(m.y, tau, xv[p].y);
            m.z = fmaf(m.z, tau, xv[p].z);
            m.w = fmaf(m.w, tau, xv[p].w);
            psum[p] = ((double)m.x + (double)m.y) + ((double)m.z + (double)m.w);
            mem[p] = m;
        }

        #pragma unroll
        for (int p = 0; p < 4; ++p) {
            double s = psum[p];
            #pragma unroll
            for (int off = 32; off > 0; off >>= 1) s += __shfl_down(s, off);
            if (ln == 0) s_part[p][wv] = s;
        }
        LDS_BARRIER();                   // B1: s_part visible to wave 0

        if (t == NT - 1) {
            // last step: nothing consumes the means; just emit spikes
            #pragma unroll
            for (int p = 0; p < 4; ++p) {
                v4f m = mem[p];
                v4f sp;
                sp.x = (m.x > 1.0f) ? 1.0f : 0.0f;   // zif(mem-1): exact
                sp.y = (m.y > 1.0f) ? 1.0f : 0.0f;
                sp.z = (m.z > 1.0f) ? 1.0f : 0.0f;
                sp.w = (m.w > 1.0f) ? 1.0f : 0.0f;
                __builtin_nontemporal_store(sp,
                    o4 + ((b * NT + t) * NC + c0 + p) * NQ + tid);
            }
            break;
        }

        // ---- publish: FIRST VMEM ops of this step for wave 0 ----
        if (tid < 4) {
            double s = (s_part[tid][0] + s_part[tid][1]) +
                       (s_part[tid][2] + s_part[tid][3]);
            double mean = s * (1.0 / 1024.0);
            unsigned long long bits = __double_as_longlong(mean);
            unsigned long long tag  = ((unsigned long long)(t + 1)) << 32;
            const int base = ((t * NB + b) * NC + c0 + tid) * 2;
            // LLC-direct, fire-and-forget; seq tag self-validates freshness
            __hip_atomic_store(&g_xw[base + 0], tag | (bits & 0xffffffffull),
                               __ATOMIC_RELAXED, __HIP_MEMORY_SCOPE_AGENT);
            __hip_atomic_store(&g_xw[base + 1], tag | (bits >> 32),
                               __ATOMIC_RELAXED, __HIP_MEMORY_SCOPE_AGENT);
        }

        // ---- prefetch t+1: loads must complete before next phase A, so
        // letting the poll's vmcnt(0) drain them overlaps their latency
        // with the sibling-skew wait (free) ----
        #pragma unroll
        for (int p = 0; p < 4; ++p)
            xv[p] = __builtin_nontemporal_load(
                x4 + ((b * NT + (t + 1)) * NC + c0 + p) * NQ + tid);

        // ---- seq-validated parallel poll (256 lanes, 1 word each) ----
        // The poll IS the fetch: spin until the word's embedded seq == t+1.
        // Queue at this point: publish + prefetch only — NO spike stores.
        {
            const int idx = ((t * NB + b) * NC + (tid >> 1)) * 2 + (tid & 1);
            const unsigned int want = (unsigned int)(t + 1);
            unsigned long long w;
            for (;;) {
                w = __hip_atomic_load(&g_xw[idx], __ATOMIC_RELAXED,
                                      __HIP_MEMORY_SCOPE_AGENT);
                if ((unsigned int)(w >> 32) == want) break;
                __builtin_amdgcn_s_sleep(1);
            }
            s_w[tid] = (unsigned int)w;
        }
        // pin program order: stores below must NOT be hoisted above the poll
        asm volatile("" ::: "memory");

        // ---- spike + NT-store + reset: AFTER the poll, fire-and-forget;
        // acks return during the next ~10 us step, never on a wait path ----
        #pragma unroll
        for (int p = 0; p < 4; ++p) {
            v4f m = mem[p];
            v4f sp;
            sp.x = (m.x > 1.0f) ? 1.0f : 0.0f;   // zif(mem-1): exact (Sterbenz)
            sp.y = (m.y > 1.0f) ? 1.0f : 0.0f;
            sp.z = (m.z > 1.0f) ? 1.0f : 0.0f;
            sp.w = (m.w > 1.0f) ? 1.0f : 0.0f;
            __builtin_nontemporal_store(sp, o4 + ((b * NT + t) * NC + c0 + p) * NQ + tid);
            m.x = (m.x > 1.0f) ? 0.0f : m.x;     // (1-spike)*mem
            m.y = (m.y > 1.0f) ? 0.0f : m.y;
            m.z = (m.z > 1.0f) ? 0.0f : m.z;
            m.w = (m.w > 1.0f) ? 0.0f : m.w;
            mem[p] = m;
        }

        LDS_BARRIER();                   // B2: s_w visible to wave 0

        // tiny MLP (128->32->1), recomputed per block for its own batch.
        // s_w reads are same-address broadcasts (no bank conflicts); w1 row
        // is per-lane contiguous float4 (L1-resident). Mean double bits are
        // reassembled exactly; summation order identical to the verified
        // kernel: cc = 0..127 ascending.
        double e = 0.0;
        if (tid < CRED) {
            const v4f* __restrict__ w1v = (const v4f*)(w1 + tid * NC);
            double acc = (double)b1[tid];
            #pragma unroll
            for (int q = 0; q < NC / 4; ++q) {
                v4f wq = w1v[q];
                #pragma unroll
                for (int k = 0; k < 4; ++k) {
                    const int c = 4 * q + k;
                    unsigned long long bits =
                        ((unsigned long long)s_w[2 * c + 1] << 32) | s_w[2 * c];
                    double xm = __longlong_as_double(bits);
                    acc += xm * (double)((k == 0) ? wq.x : (k == 1) ? wq.y
                                         : (k == 2) ? wq.z : wq.w);
                }
            }
            double emb = acc > 0.0 ? acc : 0.0;
            e = emb * (double)w2[tid];
        }
        #pragma unroll
        for (int off = 32; off > 0; off >>= 1) e += __shfl_down(e, off);
        if (tid == 0) {
            double z = e + (double)b2[0];
            s_tau = (float)(1.0 / (1.0 + exp(-z)));
        }
        LDS_BARRIER();                   // B3: s_tau visible to all waves
        tau = s_tau;
    }
}

extern "C" void kernel_launch(void* const* d_in, const int* in_sizes, int n_in,
                              void* d_out, int out_size, void* d_ws, size_t ws_size,
                              hipStream_t stream) {
    const float* x  = (const float*)d_in[0];
    const float* w1 = (const float*)d_in[1];
    const float* b1 = (const float*)d_in[2];
    const float* w2 = (const float*)d_in[3];
    const float* b2 = (const float*)d_in[4];
    float* out      = (float*)d_out;

    // zero the seq-tagged word buffer (stream-ordered before the main kernel)
    hipLaunchKernelGGL(lif_init, dim3((NWORDS + 255) / 256), dim3(256),
                       0, stream);
    // plain launch — no cooperative protocol overhead
    hipLaunchKernelGGL(dynamic_lif, dim3(NB * NC / 4), dim3(256), 0, stream,
                       x, w1, b1, w2, b2, out);
}